// Round 4
// baseline (410.701 us; speedup 1.0000x reference)
//
#include <hip/hip_runtime.h>
#include <hip/hip_bf16.h>

// Implicit-GEMM conv: M = 32*54*54 = 93312, N = 256 (co), K = 9*256 = 2304.
// bf16 MFMA (16x16x32), 128x128 tile, BK=32.
// R4: B (Wt, 1.15 MB, L2-resident) bypasses LDS -> direct global->VGPR
//     fragment loads, prefetched one k-step ahead (issued just after the
//     barrier, consumed after the next barrier). A stays via glds LDS
//     double-buffer. LDS traffic per block-step: 48 KB -> 24 KB.

typedef __bf16 bf16x8 __attribute__((ext_vector_type(8)));
typedef float f32x4 __attribute__((ext_vector_type(4)));

#define GLOBAL_AS __attribute__((address_space(1)))
#define LDS_AS __attribute__((address_space(3)))

static __device__ __forceinline__ void glds16(const void* g, void* l) {
    __builtin_amdgcn_global_load_lds((const GLOBAL_AS unsigned int*)g,
                                     (LDS_AS unsigned int*)l, 16, 0, 0);
}

static __device__ __forceinline__ unsigned short f2bf(float f) {
    unsigned int u = __float_as_uint(f);
    unsigned int r = u + 0x7FFFu + ((u >> 16) & 1u);  // RNE
    return (unsigned short)(r >> 16);
}

// ---- combined conversion: blocks [0,12544) convert x, [12544,12800) convert w ----
__global__ void cvt_xw(const float* __restrict__ x, unsigned short* __restrict__ xb,
                       const float* __restrict__ w, unsigned short* __restrict__ wt) {
    const int NXB = 32 * 56 * 56 * 256 / (256 * 8);  // 12544
    if (blockIdx.x < NXB) {
        int i = (blockIdx.x * 256 + threadIdx.x) * 8;
        const float4* p = (const float4*)(x + i);
        float4 a = p[0], b = p[1];
        uint4 v;
        v.x = (unsigned)f2bf(a.x) | ((unsigned)f2bf(a.y) << 16);
        v.y = (unsigned)f2bf(a.z) | ((unsigned)f2bf(a.w) << 16);
        v.z = (unsigned)f2bf(b.x) | ((unsigned)f2bf(b.y) << 16);
        v.w = (unsigned)f2bf(b.z) | ((unsigned)f2bf(b.w) << 16);
        *(uint4*)(xb + i) = v;
    } else {
        int co = blockIdx.x - NXB;
        int ci = threadIdx.x;
        const float* src = w + co * 2304 + ci * 9;
        unsigned short* dst = wt + co * 2304 + ci;
#pragma unroll
        for (int khw = 0; khw < 9; ++khw) {
            float v = src[khw];
            v = (fabsf(v) < 0.01f) ? 0.0f : v;
            dst[khw * 256] = f2bf(v);
        }
    }
}

// LDS swizzle: row's global k-chunk g (8 bf16) lives at slot g ^ key(row mod 16).
static __device__ __forceinline__ int swz_key(int r) {
    return (r & 3) ^ ((r >> 2) & 3);
}

// global A-tile element offset for k-chunk kcn (0..71)
static __device__ __forceinline__ int a_off(int kcn) {
    int khw = kcn >> 3;
    int kh = (khw * 11) >> 5;  // khw/3 for 0..8
    int kw = khw - kh * 3;
    return ((kh * 56 + kw) << 8) + (kcn & 7) * 32;
}

// ---- GEMM: Out[m][co] = sum_k A[m][k]*Wt[co][k] + bias[co] ----
__global__ __launch_bounds__(256, 3) void conv_gemm(
    const unsigned short* __restrict__ Xb,   // bf16 bits [32*56*56*256]
    const unsigned short* __restrict__ Wt,   // bf16 bits [256][2304]
    const float* __restrict__ bias,          // [256]
    float* __restrict__ Out)                 // [93312][256]
{
    __shared__ __align__(16) unsigned short As[2][128 * 32];  // A only, 16 KB

    const int tid  = threadIdx.x;
    const int lane = tid & 63;
    const int wave = tid >> 6;

    // XCD-contiguous remap (d -> XCD d%8): XCD x owns a contiguous virtual range.
    const int bx  = blockIdx.x;
    const int xcd = bx & 7;
    const int slt = bx >> 3;
    const int v   = xcd * 182 + (xcd < 2 ? xcd : 2) + slt;  // 1458 = 8*182+2
    const int m0  = (v >> 1) * 128;
    const int co0 = (v & 1) * 128;

    // A staging: lane covers tile row (r*64 + wave*16 + srow), swizzled k-chunk
    const int srow = lane >> 2;
    const int scol = ((lane & 3) ^ swz_key(srow)) * 8;

    const unsigned short* a_src[2];
#pragma unroll
    for (int r = 0; r < 2; ++r) {
        int row = r * 64 + wave * 16 + srow;
        int m = m0 + row;
        int n = m / 2916;
        int rem = m - n * 2916;
        int oh = rem / 54;
        int ow = rem - oh * 54;
        a_src[r] = Xb + (((n * 56 + oh) * 56 + ow) << 8) + scol;  // kh=kw=0
    }

    const int fm = lane & 15;  // A-row / B-col within 16
    const int fq = lane >> 4;  // global k-chunk index
    const int wm = (wave >> 1) * 64;
    const int wn = (wave & 1) * 64;
    const int slot8 = (fq ^ swz_key(fm)) * 8;  // swizzled LDS column (elems)

    // B lane base: Wt[co0+wn+fm][fq*8]; frag ni at +ni*16 rows, step kc at +kc*32
    const unsigned short* b_lane = Wt + (co0 + wn + fm) * 2304 + fq * 8;

    f32x4 acc[4][4];
#pragma unroll
    for (int i = 0; i < 4; ++i)
#pragma unroll
        for (int j = 0; j < 4; ++j)
            acc[i][j] = (f32x4){0.f, 0.f, 0.f, 0.f};

    // prologue: stage A(0) -> As[0], load B(0) -> b0
#pragma unroll
    for (int r = 0; r < 2; ++r)
        glds16(a_src[r], &As[0][wave * 512 + r * 2048]);
    bf16x8 b0[4], b1[4];
#pragma unroll
    for (int ni = 0; ni < 4; ++ni)
        b0[ni] = *(const bf16x8*)(b_lane + ni * 16 * 2304);

#pragma unroll 1
    for (int kc = 0; kc < 72; kc += 2) {
        // ---- even step: compute kc from As[0]/b0, prefetch kc+1 -> As[1]/b1 ----
        __syncthreads();  // drains A-glds(kc) and B(kc) loads (issued last iter)
        {
            const int kcn = kc + 1;  // kc<=70 -> kcn<=71, always valid
            const int ao = a_off(kcn), bo = kcn * 32;
#pragma unroll
            for (int r = 0; r < 2; ++r)
                glds16(a_src[r] + ao, &As[1][wave * 512 + r * 2048]);
#pragma unroll
            for (int ni = 0; ni < 4; ++ni)
                b1[ni] = *(const bf16x8*)(b_lane + ni * 16 * 2304 + bo);
        }
        {
            bf16x8 af[4];
#pragma unroll
            for (int mi = 0; mi < 4; ++mi)
                af[mi] = *(const bf16x8*)&As[0][(wm + mi * 16 + fm) * 32 + slot8];
#pragma unroll
            for (int mi = 0; mi < 4; ++mi)
#pragma unroll
                for (int ni = 0; ni < 4; ++ni)
                    acc[mi][ni] = __builtin_amdgcn_mfma_f32_16x16x32_bf16(
                        af[mi], b0[ni], acc[mi][ni], 0, 0, 0);
        }

        // ---- odd step: compute kc+1 from As[1]/b1, prefetch kc+2 -> As[0]/b0 ----
        __syncthreads();
        if (kc + 2 < 72) {
            const int kcn = kc + 2;
            const int ao = a_off(kcn), bo = kcn * 32;
#pragma unroll
            for (int r = 0; r < 2; ++r)
                glds16(a_src[r] + ao, &As[0][wave * 512 + r * 2048]);
#pragma unroll
            for (int ni = 0; ni < 4; ++ni)
                b0[ni] = *(const bf16x8*)(b_lane + ni * 16 * 2304 + bo);
        }
        {
            bf16x8 af[4];
#pragma unroll
            for (int mi = 0; mi < 4; ++mi)
                af[mi] = *(const bf16x8*)&As[1][(wm + mi * 16 + fm) * 32 + slot8];
#pragma unroll
            for (int mi = 0; mi < 4; ++mi)
#pragma unroll
                for (int ni = 0; ni < 4; ++ni)
                    acc[mi][ni] = __builtin_amdgcn_mfma_f32_16x16x32_bf16(
                        af[mi], b1[ni], acc[mi][ni], 0, 0, 0);
        }
    }

    // epilogue: D col = lane&15 (co), row = (lane>>4)*4 + reg (m); fuse bias
    float bv[4];
#pragma unroll
    for (int ni = 0; ni < 4; ++ni) bv[ni] = bias[co0 + wn + ni * 16 + fm];
#pragma unroll
    for (int mi = 0; mi < 4; ++mi) {
#pragma unroll
        for (int reg = 0; reg < 4; ++reg) {
            int m = m0 + wm + mi * 16 + fq * 4 + reg;
            float* orow = Out + m * 256 + co0 + wn + fm;
#pragma unroll
            for (int ni = 0; ni < 4; ++ni)
                orow[ni * 16] = acc[mi][ni][reg] + bv[ni];
        }
    }
}

extern "C" void kernel_launch(void* const* d_in, const int* in_sizes, int n_in,
                              void* d_out, int out_size, void* d_ws, size_t ws_size,
                              hipStream_t stream) {
    const float* x    = (const float*)d_in[0];  // (32,56,56,256) fp32
    const float* w    = (const float*)d_in[1];  // (256,256,3,3) fp32
    const float* bias = (const float*)d_in[2];  // (256,) fp32
    float* out = (float*)d_out;                 // (32,54,54,256) fp32

    const int NX = 32 * 56 * 56 * 256;  // 25,690,112
    unsigned short* xb = (unsigned short*)d_ws;
    unsigned short* wt = xb + NX;

    cvt_xw<<<NX / (256 * 8) + 256, 256, 0, stream>>>(x, xb, w, wt);
    conv_gemm<<<729 * 2, 256, 0, stream>>>(xb, wt, bias, out);
}